// Round 1
// baseline (269.187 us; speedup 1.0000x reference)
//
#include <hip/hip_runtime.h>
#include <hip/hip_bf16.h>

// InfoNCE loss, B=4096 D=768 N=8192, T=0.5, fp32 in, fp32 scalar out.
// Strategy: normalize->bf16, fused MFMA GEMM + exp-rowsum (no NxN materialization),
// fp32 positives, final logsumexp-mean reduce.

#define B_SZ 4096
#define D_SZ 768
#define N_SZ 8192
constexpr float INV_T = 2.0f;  // 1/temperature

typedef short bf16x8 __attribute__((ext_vector_type(8)));
typedef float f32x4 __attribute__((ext_vector_type(4)));

// ---- block-wide sum over 256 threads (4 waves), result broadcast to all ----
__device__ inline float block_reduce_256(float v, float* red) {
    const int lane = threadIdx.x & 63;
    const int w = threadIdx.x >> 6;
#pragma unroll
    for (int off = 32; off > 0; off >>= 1) v += __shfl_down(v, off, 64);
    if (lane == 0) red[w] = v;
    __syncthreads();
    return red[0] + red[1] + red[2] + red[3];
}

// ---- 1) row-normalize concat([h1;h2]) -> bf16 hn, save norms ----
__global__ __launch_bounds__(256) void normalize_k(const float* __restrict__ h1,
                                                   const float* __restrict__ h2,
                                                   __hip_bfloat16* __restrict__ hn,
                                                   float* __restrict__ norms) {
    __shared__ float red[4];
    const int row = blockIdx.x;
    const int tid = threadIdx.x;
    const float* src = (row < B_SZ) ? (h1 + (size_t)row * D_SZ)
                                    : (h2 + (size_t)(row - B_SZ) * D_SZ);
    float v0 = src[tid], v1 = src[tid + 256], v2 = src[tid + 512];
    float tot = block_reduce_256(v0 * v0 + v1 * v1 + v2 * v2, red);
    float nrm = fmaxf(sqrtf(tot), 1e-8f);
    float inv = 1.0f / nrm;
    if (tid == 0) norms[row] = nrm;
    __hip_bfloat16* dst = hn + (size_t)row * D_SZ;
    dst[tid]       = __float2bfloat16(v0 * inv);
    dst[tid + 256] = __float2bfloat16(v1 * inv);
    dst[tid + 512] = __float2bfloat16(v2 * inv);
}

// ---- 2) positives in exact fp32: pos[i] = pos[i+B] = dot(h1[i],h2[i])/(n_i n_{i+B}) / T ----
__global__ __launch_bounds__(256) void pos_k(const float* __restrict__ h1,
                                             const float* __restrict__ h2,
                                             const float* __restrict__ norms,
                                             float* __restrict__ pos) {
    __shared__ float red[4];
    const int i = blockIdx.x;
    const int tid = threadIdx.x;
    const float* a = h1 + (size_t)i * D_SZ;
    const float* b = h2 + (size_t)i * D_SZ;
    float d = a[tid] * b[tid] + a[tid + 256] * b[tid + 256] + a[tid + 512] * b[tid + 512];
    float tot = block_reduce_256(d, red);
    if (tid == 0) {
        float p = tot / (norms[i] * norms[i + B_SZ]) * INV_T;
        pos[i] = p;
        pos[i + B_SZ] = p;
    }
}

// ---- 3) fused sim-GEMM + exp-rowsum ----
// 128x128 tile per block, 4 waves, each wave: 32 rows x 128 cols (2 m-tiles x 8 n-tiles
// of 16x16x32 bf16 MFMA). LDS rows padded to LDK=40 bf16 for bank-uniform ds_read_b128.
#define BM 128
#define BN 128
#define BK 32
#define LDK 40

__global__ __launch_bounds__(256) void gemm_reduce_k(const __hip_bfloat16* __restrict__ hn,
                                                     float* __restrict__ rowsum) {
    __shared__ __align__(16) unsigned short As[BM * LDK];
    __shared__ __align__(16) unsigned short Bs[BN * LDK];
    const int colBase = blockIdx.x * BN;
    const int rowBase = blockIdx.y * BM;
    const int tid = threadIdx.x;
    const int wave = tid >> 6;
    const int lane = tid & 63;
    const int q = lane >> 4;    // quad: k-group and C-row group
    const int l16 = lane & 15;  // C column within 16-tile

    f32x4 acc[2][8];
#pragma unroll
    for (int mt = 0; mt < 2; ++mt)
#pragma unroll
        for (int nt = 0; nt < 8; ++nt) acc[mt][nt] = (f32x4){0.f, 0.f, 0.f, 0.f};

    for (int k0 = 0; k0 < D_SZ; k0 += BK) {
        __syncthreads();  // protect prior iteration's LDS reads
#pragma unroll
        for (int cc = 0; cc < 2; ++cc) {
            int c = tid + cc * 256;      // chunk id 0..511: 16B each
            int r = c >> 2, g = c & 3;   // tile row, 8-elem k-group
            float4 va = *(const float4*)(hn + (size_t)(rowBase + r) * D_SZ + k0 + g * 8);
            float4 vb = *(const float4*)(hn + (size_t)(colBase + r) * D_SZ + k0 + g * 8);
            *(float4*)&As[r * LDK + g * 8] = va;
            *(float4*)&Bs[r * LDK + g * 8] = vb;
        }
        __syncthreads();
        // A-frag: lane holds A[m=l16][k=q*8+j]; B-frag identical pattern (B^T layout)
        bf16x8 a0 = *(const bf16x8*)&As[(wave * 32 + l16) * LDK + q * 8];
        bf16x8 a1 = *(const bf16x8*)&As[(wave * 32 + 16 + l16) * LDK + q * 8];
#pragma unroll
        for (int nt = 0; nt < 8; ++nt) {
            bf16x8 b = *(const bf16x8*)&Bs[(nt * 16 + l16) * LDK + q * 8];
            acc[0][nt] = __builtin_amdgcn_mfma_f32_16x16x32_bf16(a0, b, acc[0][nt], 0, 0, 0);
            acc[1][nt] = __builtin_amdgcn_mfma_f32_16x16x32_bf16(a1, b, acc[1][nt], 0, 0, 0);
        }
    }

    // epilogue: C/D layout col=l16, row=q*4+reg. Per-row exp-sum, mask diagonal.
#pragma unroll
    for (int mt = 0; mt < 2; ++mt) {
#pragma unroll
        for (int r = 0; r < 4; ++r) {
            int row = rowBase + wave * 32 + mt * 16 + q * 4 + r;
            float s = 0.f;
#pragma unroll
            for (int nt = 0; nt < 8; ++nt) {
                int col = colBase + nt * 16 + l16;
                float e = __expf(acc[mt][nt][r] * INV_T);
                s += (row == col) ? 0.f : e;
            }
#pragma unroll
            for (int m = 1; m < 16; m <<= 1) s += __shfl_xor(s, m, 16);
            if (l16 == 0) atomicAdd(&rowsum[row], s);
        }
    }
}

// ---- 4) loss = mean(log(rowsum) - pos) ----
__global__ __launch_bounds__(256) void finalize_k(const float* __restrict__ rowsum,
                                                  const float* __restrict__ pos,
                                                  float* __restrict__ out) {
    __shared__ float red[4];
    float s = 0.f;
    for (int r = threadIdx.x; r < N_SZ; r += 256) s += logf(rowsum[r]) - pos[r];
    float tot = block_reduce_256(s, red);
    if (threadIdx.x == 0) out[0] = tot * (1.0f / (float)N_SZ);
}

extern "C" void kernel_launch(void* const* d_in, const int* in_sizes, int n_in,
                              void* d_out, int out_size, void* d_ws, size_t ws_size,
                              hipStream_t stream) {
    const float* h1 = (const float*)d_in[0];
    const float* h2 = (const float*)d_in[1];
    float* out = (float*)d_out;

    char* ws = (char*)d_ws;
    __hip_bfloat16* hn = (__hip_bfloat16*)ws;                       // N*D*2 = 12,582,912 B
    float* norms  = (float*)(ws + (size_t)N_SZ * D_SZ * 2);          // 32 KB
    float* pos    = (float*)(ws + (size_t)N_SZ * D_SZ * 2 + 32768);  // 32 KB
    float* rowsum = (float*)(ws + (size_t)N_SZ * D_SZ * 2 + 65536);  // 32 KB

    hipMemsetAsync(rowsum, 0, N_SZ * sizeof(float), stream);
    normalize_k<<<N_SZ, 256, 0, stream>>>(h1, h2, hn, norms);
    pos_k<<<B_SZ, 256, 0, stream>>>(h1, h2, norms, pos);
    dim3 grid(N_SZ / BN, N_SZ / BM);
    gemm_reduce_k<<<grid, 256, 0, stream>>>(hn, rowsum);
    finalize_k<<<1, 256, 0, stream>>>(rowsum, pos, out);
}

// Round 2
// 222.743 us; speedup vs baseline: 1.2085x; 1.2085x over previous
//
#include <hip/hip_runtime.h>
#include <hip/hip_bf16.h>

// InfoNCE loss, B=4096 D=768 N=8192, T=0.5, fp32 in, fp32 scalar out.
// R2: m97-style staging (global_load_lds width=16, unpadded BK=32) + fused prep.

#define B_SZ 4096
#define D_SZ 768
#define N_SZ 8192
constexpr float INV_T = 2.0f;  // 1/temperature

typedef short bf16x8 __attribute__((ext_vector_type(8)));
typedef float f32x4 __attribute__((ext_vector_type(4)));
typedef __attribute__((address_space(1))) const unsigned int gu32;
typedef __attribute__((address_space(3))) unsigned int lu32;

__device__ inline void async16(const void* g, void* l) {
    // HW semantics: per-lane global addr, wave-uniform LDS base; lane i lands at base + i*16.
    __builtin_amdgcn_global_load_lds((gu32*)g, (lu32*)l, 16, 0, 0);
}

// ---- 1) fused: norms + positives + bf16 normalized rows, one block per pair i ----
__global__ __launch_bounds__(256) void prep_k(const float* __restrict__ h1,
                                              const float* __restrict__ h2,
                                              __hip_bfloat16* __restrict__ hn,
                                              float* __restrict__ pos) {
    __shared__ float red[3][4];
    const int i = blockIdx.x;
    const int tid = threadIdx.x;
    const float* a = h1 + (size_t)i * D_SZ;
    const float* b = h2 + (size_t)i * D_SZ;
    float av[3], bv[3];
    float sa = 0.f, sb = 0.f, dt = 0.f;
#pragma unroll
    for (int j = 0; j < 3; ++j) {
        av[j] = a[tid + j * 256];
        bv[j] = b[tid + j * 256];
        sa += av[j] * av[j];
        sb += bv[j] * bv[j];
        dt += av[j] * bv[j];
    }
#pragma unroll
    for (int off = 32; off > 0; off >>= 1) {
        sa += __shfl_down(sa, off, 64);
        sb += __shfl_down(sb, off, 64);
        dt += __shfl_down(dt, off, 64);
    }
    const int lane = tid & 63, w = tid >> 6;
    if (lane == 0) { red[0][w] = sa; red[1][w] = sb; red[2][w] = dt; }
    __syncthreads();
    sa = red[0][0] + red[0][1] + red[0][2] + red[0][3];
    sb = red[1][0] + red[1][1] + red[1][2] + red[1][3];
    dt = red[2][0] + red[2][1] + red[2][2] + red[2][3];
    const float n1 = fmaxf(sqrtf(sa), 1e-8f), n2 = fmaxf(sqrtf(sb), 1e-8f);
    const float i1 = 1.0f / n1, i2 = 1.0f / n2;
    __hip_bfloat16* d1 = hn + (size_t)i * D_SZ;
    __hip_bfloat16* d2 = hn + (size_t)(i + B_SZ) * D_SZ;
#pragma unroll
    for (int j = 0; j < 3; ++j) {
        d1[tid + j * 256] = __float2bfloat16(av[j] * i1);
        d2[tid + j * 256] = __float2bfloat16(bv[j] * i2);
    }
    if (tid == 0) {
        float p = dt * i1 * i2 * INV_T;
        pos[i] = p;
        pos[i + B_SZ] = p;
    }
}

// ---- 2) fused sim-GEMM + exp-rowsum ----
// 128x128 tile, 4 waves, 2x8 16x16x32 bf16 MFMA per wave. Unpadded LDS (BK=32,
// 64 B/row) so global_load_lds width-16 lands lane l at row l>>2, chunk l&3.
#define BM 128
#define BN 128
#define BK 32

__global__ __launch_bounds__(256) void gemm_reduce_k(const __hip_bfloat16* __restrict__ hn,
                                                     float* __restrict__ rowsum) {
    __shared__ __align__(16) unsigned short As[BM * BK];
    __shared__ __align__(16) unsigned short Bs[BN * BK];
    const int colBase = blockIdx.x * BN;
    const int rowBase = blockIdx.y * BM;
    const int tid = threadIdx.x;
    const int wave = tid >> 6;
    const int lane = tid & 63;
    const int q = lane >> 4;    // quad
    const int l16 = lane & 15;
    // staging: wave owns windows (wave*2) and (wave*2+1); each window = 16 rows x 64 B.
    const int lrow = lane >> 2;   // row within window
    const int lelem = (lane & 3) * 8;  // bf16 offset of this lane's 16 B chunk

    f32x4 acc[2][8];
#pragma unroll
    for (int mt = 0; mt < 2; ++mt)
#pragma unroll
        for (int nt = 0; nt < 8; ++nt) acc[mt][nt] = (f32x4){0.f, 0.f, 0.f, 0.f};

    const int w0 = wave * 2, w1 = wave * 2 + 1;
    const __hip_bfloat16* gA0 = hn + (size_t)(rowBase + w0 * 16 + lrow) * D_SZ + lelem;
    const __hip_bfloat16* gA1 = hn + (size_t)(rowBase + w1 * 16 + lrow) * D_SZ + lelem;
    const __hip_bfloat16* gB0 = hn + (size_t)(colBase + w0 * 16 + lrow) * D_SZ + lelem;
    const __hip_bfloat16* gB1 = hn + (size_t)(colBase + w1 * 16 + lrow) * D_SZ + lelem;

    for (int k0 = 0; k0 < D_SZ; k0 += BK) {
        __syncthreads();  // prior iteration's LDS reads complete
        async16(gA0 + k0, &As[w0 * 512]);
        async16(gA1 + k0, &As[w1 * 512]);
        async16(gB0 + k0, &Bs[w0 * 512]);
        async16(gB1 + k0, &Bs[w1 * 512]);
        __syncthreads();  // staging complete (compiler drains vmcnt before barrier)

        bf16x8 a0 = *(const bf16x8*)&As[(wave * 32 + l16) * BK + q * 8];
        bf16x8 a1 = *(const bf16x8*)&As[(wave * 32 + 16 + l16) * BK + q * 8];
#pragma unroll
        for (int nt = 0; nt < 8; ++nt) {
            bf16x8 b = *(const bf16x8*)&Bs[(nt * 16 + l16) * BK + q * 8];
            acc[0][nt] = __builtin_amdgcn_mfma_f32_16x16x32_bf16(a0, b, acc[0][nt], 0, 0, 0);
            acc[1][nt] = __builtin_amdgcn_mfma_f32_16x16x32_bf16(a1, b, acc[1][nt], 0, 0, 0);
        }
    }

    // epilogue: C/D layout col=l16, row=q*4+reg. Per-row exp-sum, mask diagonal.
#pragma unroll
    for (int mt = 0; mt < 2; ++mt) {
#pragma unroll
        for (int r = 0; r < 4; ++r) {
            int row = rowBase + wave * 32 + mt * 16 + q * 4 + r;
            float s = 0.f;
#pragma unroll
            for (int nt = 0; nt < 8; ++nt) {
                int col = colBase + nt * 16 + l16;
                float e = __expf(acc[mt][nt][r] * INV_T);
                s += (row == col) ? 0.f : e;
            }
#pragma unroll
            for (int m = 1; m < 16; m <<= 1) s += __shfl_xor(s, m, 16);
            if (l16 == 0) atomicAdd(&rowsum[row], s);
        }
    }
}

// ---- 3) loss = mean(log(rowsum) - pos) ----
__global__ __launch_bounds__(256) void finalize_k(const float* __restrict__ rowsum,
                                                  const float* __restrict__ pos,
                                                  float* __restrict__ out) {
    __shared__ float red[4];
    float s = 0.f;
    for (int r = threadIdx.x; r < N_SZ; r += 256) s += logf(rowsum[r]) - pos[r];
    const int lane = threadIdx.x & 63, w = threadIdx.x >> 6;
#pragma unroll
    for (int off = 32; off > 0; off >>= 1) s += __shfl_down(s, off, 64);
    if (lane == 0) red[w] = s;
    __syncthreads();
    if (threadIdx.x == 0)
        out[0] = (red[0] + red[1] + red[2] + red[3]) * (1.0f / (float)N_SZ);
}

extern "C" void kernel_launch(void* const* d_in, const int* in_sizes, int n_in,
                              void* d_out, int out_size, void* d_ws, size_t ws_size,
                              hipStream_t stream) {
    const float* h1 = (const float*)d_in[0];
    const float* h2 = (const float*)d_in[1];
    float* out = (float*)d_out;

    char* ws = (char*)d_ws;
    __hip_bfloat16* hn = (__hip_bfloat16*)ws;                        // N*D*2 = 12,582,912 B
    float* pos    = (float*)(ws + (size_t)N_SZ * D_SZ * 2);           // 32 KB
    float* rowsum = (float*)(ws + (size_t)N_SZ * D_SZ * 2 + 32768);   // 32 KB

    hipMemsetAsync(rowsum, 0, N_SZ * sizeof(float), stream);
    prep_k<<<B_SZ, 256, 0, stream>>>(h1, h2, hn, pos);
    dim3 grid(N_SZ / BN, N_SZ / BM);
    gemm_reduce_k<<<grid, 256, 0, stream>>>(hn, rowsum);
    finalize_k<<<1, 256, 0, stream>>>(rowsum, pos, out);
}

// Round 3
// 163.261 us; speedup vs baseline: 1.6488x; 1.3643x over previous
//
#include <hip/hip_runtime.h>
#include <hip/hip_bf16.h>

// InfoNCE loss, B=4096 D=768 N=8192, T=0.5, fp32 in, fp32 scalar out.
// R3: symmetric-GEMM — only upper-triangular tile pairs (2080 of 4096 blocks);
// off-diag blocks feed both row-sums and (by symmetry) col-sums. m97 staging.

#define B_SZ 4096
#define D_SZ 768
#define N_SZ 8192
constexpr float INV_T = 2.0f;  // 1/temperature

typedef short bf16x8 __attribute__((ext_vector_type(8)));
typedef float f32x4 __attribute__((ext_vector_type(4)));
typedef __attribute__((address_space(1))) const unsigned int gu32;
typedef __attribute__((address_space(3))) unsigned int lu32;

__device__ inline void async16(const void* g, void* l) {
    // per-lane global addr, wave-uniform LDS base; lane i lands at base + i*16.
    __builtin_amdgcn_global_load_lds((gu32*)g, (lu32*)l, 16, 0, 0);
}

// ---- 1) fused: norms + positives + bf16 normalized rows + rowsum zeroing ----
__global__ __launch_bounds__(256) void prep_k(const float* __restrict__ h1,
                                              const float* __restrict__ h2,
                                              __hip_bfloat16* __restrict__ hn,
                                              float* __restrict__ pos,
                                              float* __restrict__ rowsum) {
    __shared__ float red[3][4];
    const int i = blockIdx.x;
    const int tid = threadIdx.x;
    const float* a = h1 + (size_t)i * D_SZ;
    const float* b = h2 + (size_t)i * D_SZ;
    float av[3], bv[3];
    float sa = 0.f, sb = 0.f, dt = 0.f;
#pragma unroll
    for (int j = 0; j < 3; ++j) {
        av[j] = a[tid + j * 256];
        bv[j] = b[tid + j * 256];
        sa += av[j] * av[j];
        sb += bv[j] * bv[j];
        dt += av[j] * bv[j];
    }
#pragma unroll
    for (int off = 32; off > 0; off >>= 1) {
        sa += __shfl_down(sa, off, 64);
        sb += __shfl_down(sb, off, 64);
        dt += __shfl_down(dt, off, 64);
    }
    const int lane = tid & 63, w = tid >> 6;
    if (lane == 0) { red[0][w] = sa; red[1][w] = sb; red[2][w] = dt; }
    __syncthreads();
    sa = red[0][0] + red[0][1] + red[0][2] + red[0][3];
    sb = red[1][0] + red[1][1] + red[1][2] + red[1][3];
    dt = red[2][0] + red[2][1] + red[2][2] + red[2][3];
    const float n1 = fmaxf(sqrtf(sa), 1e-8f), n2 = fmaxf(sqrtf(sb), 1e-8f);
    const float i1 = 1.0f / n1, i2 = 1.0f / n2;
    __hip_bfloat16* d1 = hn + (size_t)i * D_SZ;
    __hip_bfloat16* d2 = hn + (size_t)(i + B_SZ) * D_SZ;
#pragma unroll
    for (int j = 0; j < 3; ++j) {
        d1[tid + j * 256] = __float2bfloat16(av[j] * i1);
        d2[tid + j * 256] = __float2bfloat16(bv[j] * i2);
    }
    if (tid == 0) {
        float p = dt * i1 * i2 * INV_T;
        pos[i] = p;
        pos[i + B_SZ] = p;
        rowsum[i] = 0.f;          // ws is re-poisoned each call; zero here
        rowsum[i + B_SZ] = 0.f;
    }
}

// ---- 2) symmetric fused sim-GEMM + exp-rowsum ----
// 128x128 tile, 4 waves, 2x8 16x16x32 bf16 MFMA per wave. Unpadded LDS (BK=32,
// 64 B/row): global_load_lds w16 lands lane l at row l>>2, chunk l&3.
// Grid: 2080 upper-triangular tile pairs (ty<=tx).
#define BM 128
#define BN 128
#define BK 32

__global__ __launch_bounds__(256) void gemm_reduce_k(const __hip_bfloat16* __restrict__ hn,
                                                     float* __restrict__ rowsum) {
    __shared__ __align__(16) unsigned short As[BM * BK];
    __shared__ __align__(16) unsigned short Bs[BN * BK];
    // triangular index -> (ty, tx), ty <= tx
    const int b = blockIdx.x;
    int tx = (int)((sqrtf(8.0f * (float)b + 1.0f) - 1.0f) * 0.5f);
    while ((tx + 1) * (tx + 2) / 2 <= b) ++tx;
    while (tx * (tx + 1) / 2 > b) --tx;
    const int ty = b - tx * (tx + 1) / 2;
    const int rowBase = ty * BM;
    const int colBase = tx * BN;
    const bool diagBlk = (ty == tx);

    const int tid = threadIdx.x;
    const int wave = tid >> 6;
    const int lane = tid & 63;
    const int q = lane >> 4;
    const int l16 = lane & 15;
    const int lrow = lane >> 2;
    const int lelem = (lane & 3) * 8;

    f32x4 acc[2][8];
#pragma unroll
    for (int mt = 0; mt < 2; ++mt)
#pragma unroll
        for (int nt = 0; nt < 8; ++nt) acc[mt][nt] = (f32x4){0.f, 0.f, 0.f, 0.f};

    const int w0 = wave * 2, w1 = wave * 2 + 1;
    const __hip_bfloat16* gA0 = hn + (size_t)(rowBase + w0 * 16 + lrow) * D_SZ + lelem;
    const __hip_bfloat16* gA1 = hn + (size_t)(rowBase + w1 * 16 + lrow) * D_SZ + lelem;
    const __hip_bfloat16* gB0 = hn + (size_t)(colBase + w0 * 16 + lrow) * D_SZ + lelem;
    const __hip_bfloat16* gB1 = hn + (size_t)(colBase + w1 * 16 + lrow) * D_SZ + lelem;

    for (int k0 = 0; k0 < D_SZ; k0 += BK) {
        __syncthreads();
        async16(gA0 + k0, &As[w0 * 512]);
        async16(gA1 + k0, &As[w1 * 512]);
        async16(gB0 + k0, &Bs[w0 * 512]);
        async16(gB1 + k0, &Bs[w1 * 512]);
        __syncthreads();

        bf16x8 a0 = *(const bf16x8*)&As[(wave * 32 + l16) * BK + q * 8];
        bf16x8 a1 = *(const bf16x8*)&As[(wave * 32 + 16 + l16) * BK + q * 8];
#pragma unroll
        for (int nt = 0; nt < 8; ++nt) {
            bf16x8 bfr = *(const bf16x8*)&Bs[(nt * 16 + l16) * BK + q * 8];
            acc[0][nt] = __builtin_amdgcn_mfma_f32_16x16x32_bf16(a0, bfr, acc[0][nt], 0, 0, 0);
            acc[1][nt] = __builtin_amdgcn_mfma_f32_16x16x32_bf16(a1, bfr, acc[1][nt], 0, 0, 0);
        }
    }

    // epilogue: C/D layout col=l16, row=q*4+reg. exp once -> row sums (regs) + col sums.
    float rs[2][4] = {{0.f, 0.f, 0.f, 0.f}, {0.f, 0.f, 0.f, 0.f}};
#pragma unroll
    for (int nt = 0; nt < 8; ++nt) {
        float cs = 0.f;
#pragma unroll
        for (int mt = 0; mt < 2; ++mt) {
#pragma unroll
            for (int r = 0; r < 4; ++r) {
                int row = rowBase + wave * 32 + mt * 16 + q * 4 + r;
                int col = colBase + nt * 16 + l16;
                float e = __expf(acc[mt][nt][r] * INV_T);
                e = (diagBlk && row == col) ? 0.f : e;
                rs[mt][r] += e;
                cs += e;
            }
        }
        if (!diagBlk) {
            // reduce across q-groups (rows of this wave) -> col sums for 16 cols
            cs += __shfl_xor(cs, 16, 64);
            cs += __shfl_xor(cs, 32, 64);
            if (q == 0) atomicAdd(&rowsum[colBase + nt * 16 + l16], cs);
        }
    }
#pragma unroll
    for (int mt = 0; mt < 2; ++mt) {
#pragma unroll
        for (int r = 0; r < 4; ++r) {
            float s = rs[mt][r];
#pragma unroll
            for (int m = 1; m < 16; m <<= 1) s += __shfl_xor(s, m, 16);
            if (l16 == 0)
                atomicAdd(&rowsum[rowBase + wave * 32 + mt * 16 + q * 4 + r], s);
        }
    }
}

// ---- 3) loss = mean(log(rowsum) - pos) ----
__global__ __launch_bounds__(256) void finalize_k(const float* __restrict__ rowsum,
                                                  const float* __restrict__ pos,
                                                  float* __restrict__ out) {
    __shared__ float red[4];
    float s = 0.f;
    for (int r = threadIdx.x; r < N_SZ; r += 256) s += logf(rowsum[r]) - pos[r];
    const int lane = threadIdx.x & 63, w = threadIdx.x >> 6;
#pragma unroll
    for (int off = 32; off > 0; off >>= 1) s += __shfl_down(s, off, 64);
    if (lane == 0) red[w] = s;
    __syncthreads();
    if (threadIdx.x == 0)
        out[0] = (red[0] + red[1] + red[2] + red[3]) * (1.0f / (float)N_SZ);
}

extern "C" void kernel_launch(void* const* d_in, const int* in_sizes, int n_in,
                              void* d_out, int out_size, void* d_ws, size_t ws_size,
                              hipStream_t stream) {
    const float* h1 = (const float*)d_in[0];
    const float* h2 = (const float*)d_in[1];
    float* out = (float*)d_out;

    char* ws = (char*)d_ws;
    __hip_bfloat16* hn = (__hip_bfloat16*)ws;                        // N*D*2 = 12,582,912 B
    float* pos    = (float*)(ws + (size_t)N_SZ * D_SZ * 2);           // 32 KB
    float* rowsum = (float*)(ws + (size_t)N_SZ * D_SZ * 2 + 32768);   // 32 KB

    prep_k<<<B_SZ, 256, 0, stream>>>(h1, h2, hn, pos, rowsum);
    const int nTiles = N_SZ / BN;                       // 64
    const int nBlocks = nTiles * (nTiles + 1) / 2;      // 2080
    gemm_reduce_k<<<nBlocks, 256, 0, stream>>>(hn, rowsum);
    finalize_k<<<1, 256, 0, stream>>>(rowsum, pos, out);
}